// Round 2
// baseline (3931.738 us; speedup 1.0000x reference)
//
#include <hip/hip_runtime.h>
#include <cstdint>
#include <cstddef>

// ---------------------------------------------------------------------------
// HierarchicalGNNBranch: 4 x [Lin(din,4fd)+ReLU -> Lin(4fd,fd)+ReLU -> GCNConv
//                             -> BN(eval) -> ReLU] -> global_max_pool
// Round 2: fp32 baseline, K-tail fixed (K=600 is not a multiple of BK=16 ->
// zero-fill guards on the staged loads). GEMMs: 64x128x16 LDS-tiled fp32.
// Message passing: per-call counting-sort CSR, fused +bias +BN +ReLU.
// Pool: atomicMax on uint-cast floats (post-ReLU values >= 0, out zeroed).
// ---------------------------------------------------------------------------

#define EPS_BN 1e-5f

// ============================ GEMM =========================================
// C(MxN) = act(A(MxK) @ B(KxN) + bias). Row-major. K % 8 == 0, N % 4 == 0.
// Tile: BM=64, BN=128, BK=16. 256 threads, each computes 4x8.
template <bool RELU, bool BIAS>
__global__ __launch_bounds__(256) void gemm_bias_act(
    const float* __restrict__ A, const float* __restrict__ B,
    const float* __restrict__ bias, float* __restrict__ C,
    int M, int N, int K) {
  constexpr int BM = 64, BN = 128, BK = 16;
  __shared__ __align__(16) float As[BK][BM + 4];   // row stride 68
  __shared__ __align__(16) float Bs[BK][BN + 4];   // row stride 132

  const int tid = threadIdx.x;
  const int tx = tid & 15;   // N-dir, 0..15
  const int ty = tid >> 4;   // M-dir, 0..15
  const int m0 = blockIdx.x * BM;
  const int n0 = blockIdx.y * BN;

  float acc[4][8];
#pragma unroll
  for (int i = 0; i < 4; ++i)
#pragma unroll
    for (int j = 0; j < 8; ++j) acc[i][j] = 0.f;

  // A-load: 64x16 floats = 256 float4. thread -> row tid>>2, col (tid&3)*4
  const int aRow = tid >> 2;
  const int aCol = (tid & 3) << 2;
  const bool aValid = (m0 + aRow) < M;
  const float* Aptr = A + (size_t)(m0 + aRow) * K + aCol;

  // B-load: 16x128 floats = 512 float4 -> 2 per thread.
  const int bRow = tid >> 5;          // 0..7 (and +8)
  const int bCol = (tid & 31) << 2;
  const bool bValid = (n0 + bCol) < N;  // N%4==0 -> whole float4 in bounds
  const float* Bptr = B + (size_t)bRow * N + n0 + bCol;

  for (int k0 = 0; k0 < K; k0 += BK) {
    // K-tail: K%8==0 guaranteed; zero-fill LDS for k >= K (contributes 0).
    float4 av = make_float4(0.f, 0.f, 0.f, 0.f);
    if (aValid && (k0 + aCol) < K)      // 4-wide at 4-aligned offset, K%4==0
      av = *reinterpret_cast<const float4*>(Aptr + k0);
    float4 bv0 = make_float4(0.f, 0.f, 0.f, 0.f);
    float4 bv1 = make_float4(0.f, 0.f, 0.f, 0.f);
    if (bValid) {
      if ((k0 + bRow) < K)
        bv0 = *reinterpret_cast<const float4*>(Bptr + (size_t)k0 * N);
      if ((k0 + 8 + bRow) < K)
        bv1 = *reinterpret_cast<const float4*>(Bptr + (size_t)(k0 + 8) * N);
    }
    __syncthreads();  // previous iteration's compute must be done
    As[aCol + 0][aRow] = av.x;
    As[aCol + 1][aRow] = av.y;
    As[aCol + 2][aRow] = av.z;
    As[aCol + 3][aRow] = av.w;
    *reinterpret_cast<float4*>(&Bs[bRow][bCol]) = bv0;
    *reinterpret_cast<float4*>(&Bs[bRow + 8][bCol]) = bv1;
    __syncthreads();
#pragma unroll
    for (int k = 0; k < BK; ++k) {
      float a_[4], b_[8];
      *reinterpret_cast<float4*>(a_) = *reinterpret_cast<const float4*>(&As[k][ty * 4]);
      *reinterpret_cast<float4*>(b_) = *reinterpret_cast<const float4*>(&Bs[k][tx * 8]);
      *reinterpret_cast<float4*>(b_ + 4) = *reinterpret_cast<const float4*>(&Bs[k][tx * 8 + 4]);
#pragma unroll
      for (int i = 0; i < 4; ++i)
#pragma unroll
        for (int j = 0; j < 8; ++j) acc[i][j] += a_[i] * b_[j];
    }
  }

#pragma unroll
  for (int i = 0; i < 4; ++i) {
    const int m = m0 + ty * 4 + i;
    if (m >= M) break;
    float* Crow = C + (size_t)m * N;
#pragma unroll
    for (int j = 0; j < 8; ++j) {
      const int n = n0 + tx * 8 + j;
      if (n < N) {
        float v = acc[i][j];
        if (BIAS) v += bias[n];
        if (RELU) v = fmaxf(v, 0.f);
        Crow[n] = v;
      }
    }
  }
}

// ========================= Graph preprocessing =============================
__global__ void count_deg(const int* __restrict__ dst, int E, int* __restrict__ cnt) {
  int e = blockIdx.x * blockDim.x + threadIdx.x;
  if (e < E) atomicAdd(&cnt[dst[e]], 1);
}

__global__ void compute_dinv(const int* __restrict__ cnt, float* __restrict__ dinv, int N) {
  int i = blockIdx.x * blockDim.x + threadIdx.x;
  if (i < N) dinv[i] = rsqrtf((float)(cnt[i] + 1));  // +1 self-loop; always > 0
}

// block-wise inclusive scan (256/block)
__global__ void scan_block(const int* __restrict__ cnt, int* __restrict__ partial,
                           int* __restrict__ blocksum, int N) {
  __shared__ int s[256];
  const int t = threadIdx.x;
  const int i = blockIdx.x * 256 + t;
  int v = (i < N) ? cnt[i] : 0;
  s[t] = v;
  __syncthreads();
  for (int off = 1; off < 256; off <<= 1) {
    int u = (t >= off) ? s[t - off] : 0;
    __syncthreads();
    s[t] += u;
    __syncthreads();
  }
  if (i < N) partial[i] = s[t];
  if (t == 255) blocksum[blockIdx.x] = s[255];
}

// single block: blocksum -> exclusive scan of blocksum (NB <= 256)
__global__ void scan_sums(int* __restrict__ blocksum, int NB) {
  __shared__ int s[256];
  const int t = threadIdx.x;
  int v = (t < NB) ? blocksum[t] : 0;
  s[t] = v;
  __syncthreads();
  for (int off = 1; off < 256; off <<= 1) {
    int u = (t >= off) ? s[t - off] : 0;
    __syncthreads();
    s[t] += u;
    __syncthreads();
  }
  if (t < NB) blocksum[t] = s[t] - v;  // exclusive
}

__global__ void finalize_rowptr(const int* __restrict__ partial, const int* __restrict__ blockoff,
                                int* __restrict__ rowptr, int N) {
  int i = blockIdx.x * 256 + threadIdx.x;
  if (i < N) rowptr[i + 1] = partial[i] + blockoff[blockIdx.x];
  if (i == 0) rowptr[0] = 0;
}

__global__ void fill_csr(const int* __restrict__ src, const int* __restrict__ dst, int E,
                         const int* __restrict__ rowptr, int* __restrict__ cursor,
                         int* __restrict__ colidx) {
  int e = blockIdx.x * blockDim.x + threadIdx.x;
  if (e < E) {
    int d = dst[e];
    int p = atomicAdd(&cursor[d], 1);
    colidx[rowptr[d] + p] = src[e];
  }
}

// ================= Message passing + bias + BN + ReLU ======================
// one block per dst node; threads cover columns (F <= 768)
__global__ __launch_bounds__(256) void mp_bn_relu(
    const float* __restrict__ H, const int* __restrict__ rowptr,
    const int* __restrict__ colidx, const float* __restrict__ dinv,
    const float* __restrict__ gb, const float* __restrict__ gamma,
    const float* __restrict__ beta, const float* __restrict__ mean,
    const float* __restrict__ var, float* __restrict__ out, int N, int F) {
  const int i = blockIdx.x;
  const int t = threadIdx.x;
  const float di = dinv[i];
  const int c0 = t, c1 = t + 256, c2 = t + 512;
  const float* Hi = H + (size_t)i * F;
  const float wself = di * di;
  float a0 = 0.f, a1 = 0.f, a2 = 0.f;
  if (c0 < F) a0 = wself * Hi[c0];
  if (c1 < F) a1 = wself * Hi[c1];
  if (c2 < F) a2 = wself * Hi[c2];
  const int e0 = rowptr[i], e1 = rowptr[i + 1];
  for (int e = e0; e < e1; ++e) {
    const int s = colidx[e];
    const float w = di * dinv[s];
    const float* Hs = H + (size_t)s * F;
    if (c0 < F) a0 += w * Hs[c0];
    if (c1 < F) a1 += w * Hs[c1];
    if (c2 < F) a2 += w * Hs[c2];
  }
  float* Oi = out + (size_t)i * F;
  if (c0 < F) {
    float v = (a0 + gb[c0] - mean[c0]) * rsqrtf(var[c0] + EPS_BN) * gamma[c0] + beta[c0];
    Oi[c0] = fmaxf(v, 0.f);
  }
  if (c1 < F) {
    float v = (a1 + gb[c1] - mean[c1]) * rsqrtf(var[c1] + EPS_BN) * gamma[c1] + beta[c1];
    Oi[c1] = fmaxf(v, 0.f);
  }
  if (c2 < F) {
    float v = (a2 + gb[c2] - mean[c2]) * rsqrtf(var[c2] + EPS_BN) * gamma[c2] + beta[c2];
    Oi[c2] = fmaxf(v, 0.f);
  }
}

// ========================= global max pool =================================
// values are post-ReLU (>= 0): uint-compare == float-compare; out pre-zeroed.
__global__ __launch_bounds__(256) void pool_max(const float* __restrict__ X,
                                                const int* __restrict__ batch,
                                                float* __restrict__ out, int N, int F) {
  const int i = blockIdx.x;
  const int g = batch[i];
  const float* Xi = X + (size_t)i * F;
  unsigned int* og = reinterpret_cast<unsigned int*>(out + (size_t)g * F);
  for (int c = threadIdx.x; c < F; c += blockDim.x)
    atomicMax(&og[c], __float_as_uint(Xi[c]));
}

// =========================== launch ========================================
extern "C" void kernel_launch(void* const* d_in, const int* in_sizes, int n_in,
                              void* d_out, int out_size, void* d_ws, size_t ws_size,
                              hipStream_t stream) {
  const float* x = (const float*)d_in[0];
  const int* edges = (const int*)d_in[1];
  const int* batch = (const int*)d_in[2];
  const int E = in_sizes[1] / 2;
  const int N = in_sizes[2];

  static const int FDS[4] = {80, 160, 400, 600};
  const float *wa[4], *ba[4], *wb[4], *bb[4], *gw[4], *gb[4], *gamma[4], *beta[4], *mean[4], *var[4];
  for (int i = 0; i < 4; ++i) {
    const int b = 3 + 10 * i;
    wa[i] = (const float*)d_in[b + 0];
    ba[i] = (const float*)d_in[b + 1];
    wb[i] = (const float*)d_in[b + 2];
    bb[i] = (const float*)d_in[b + 3];
    gw[i] = (const float*)d_in[b + 4];
    gb[i] = (const float*)d_in[b + 5];
    gamma[i] = (const float*)d_in[b + 6];
    beta[i] = (const float*)d_in[b + 7];
    mean[i] = (const float*)d_in[b + 8];
    var[i] = (const float*)d_in[b + 9];
  }

  // ---- workspace carve (peak live set: bufA N*2400 + bufB N*600) ----
  char* p = (char*)d_ws;
  auto alloc = [&](size_t bytes) {
    char* r = p;
    p += (bytes + 255) & ~(size_t)255;
    return r;
  };
  float* bufA = (float*)alloc((size_t)N * 2400 * sizeof(float));  // H1 (max 4*fd), reused by H3
  float* bufB = (float*)alloc((size_t)N * 600 * sizeof(float));   // H2 / layer output X
  float* bufC = bufA;  // H3 aliases H1: H1 is dead once H2 exists
  int* cnt = (int*)alloc((size_t)N * sizeof(int));
  int* cursor = (int*)alloc((size_t)N * sizeof(int));
  int* partial = (int*)alloc((size_t)N * sizeof(int));
  int* blocksum = (int*)alloc(256 * sizeof(int));
  int* rowptr = (int*)alloc((size_t)(N + 1) * sizeof(int));
  int* colidx = (int*)alloc((size_t)E * sizeof(int));
  float* dinv = (float*)alloc((size_t)N * sizeof(float));

  const int* srcIdx = edges;
  const int* dstIdx = edges + E;

  // ---- CSR build (per call; workspace is re-poisoned every launch) ----
  hipMemsetAsync(cnt, 0, (size_t)N * sizeof(int), stream);
  hipMemsetAsync(cursor, 0, (size_t)N * sizeof(int), stream);
  hipMemsetAsync(d_out, 0, (size_t)out_size * sizeof(float), stream);

  const int EB = (E + 255) / 256;
  const int NB = (N + 255) / 256;
  count_deg<<<EB, 256, 0, stream>>>(dstIdx, E, cnt);
  compute_dinv<<<NB, 256, 0, stream>>>(cnt, dinv, N);
  scan_block<<<NB, 256, 0, stream>>>(cnt, partial, blocksum, N);
  scan_sums<<<1, 256, 0, stream>>>(blocksum, NB);
  finalize_rowptr<<<NB, 256, 0, stream>>>(partial, blocksum, rowptr, N);
  fill_csr<<<EB, 256, 0, stream>>>(srcIdx, dstIdx, E, rowptr, cursor, colidx);

  // ---- layers ----
  auto run_gemm = [&](const float* A, const float* B, const float* bias, float* C,
                      int M, int Nc, int K, bool relu_bias) {
    dim3 grid((M + 63) / 64, (Nc + 127) / 128);
    if (relu_bias)
      gemm_bias_act<true, true><<<grid, 256, 0, stream>>>(A, B, bias, C, M, Nc, K);
    else
      gemm_bias_act<false, false><<<grid, 256, 0, stream>>>(A, B, nullptr, C, M, Nc, K);
  };

  const float* X = x;
  int din = 3072;
  for (int i = 0; i < 4; ++i) {
    const int fd = FDS[i];
    const int hid = 4 * fd;
    run_gemm(X, wa[i], ba[i], bufA, N, hid, din, true);     // H1 = relu(X@wa+ba)
    run_gemm(bufA, wb[i], bb[i], bufB, N, fd, hid, true);   // H2 = relu(H1@wb+bb)
    run_gemm(bufB, gw[i], nullptr, bufC, N, fd, fd, false); // H3 = H2@gw  (bufC aliases bufA)
    mp_bn_relu<<<N, 256, 0, stream>>>(bufC, rowptr, colidx, dinv, gb[i], gamma[i],
                                      beta[i], mean[i], var[i], bufB, N, fd);
    X = bufB;
    din = fd;
  }

  pool_max<<<N, 256, 0, stream>>>(bufB, batch, (float*)d_out, N, 600);
}

// Round 3
// 2177.920 us; speedup vs baseline: 1.8053x; 1.8053x over previous
//
#include <hip/hip_runtime.h>
#include <cstdint>
#include <cstddef>

// ---------------------------------------------------------------------------
// Round 3: split-bf16 MFMA GEMMs (A=A_hi+A_lo, B=B_hi+B_lo, 3 MFMAs, fp32 acc).
// Activations stored pre-split (hi/lo bf16). Weights pre-split + pre-transposed
// to [n][k]. Layer-0 GEMM splits fp32 x on the fly in staging.
// MP: CSR gather-sum fused with +bias +BN +ReLU, writes split bf16.
// Pool: atomicMax on uint-cast floats (values >= 0, out zeroed).
// ---------------------------------------------------------------------------

#define EPS_BN 1e-5f

typedef unsigned short u16;
typedef short short8 __attribute__((ext_vector_type(8)));
typedef u16 u16x8 __attribute__((ext_vector_type(8)));
typedef float fx4 __attribute__((ext_vector_type(4)));

__device__ __forceinline__ u16 bf16_rn(float f) {
  unsigned u = __float_as_uint(f);
  return (u16)((u + 0x7FFFu + ((u >> 16) & 1u)) >> 16);
}
__device__ __forceinline__ float bf16_f(u16 h) {
  return __uint_as_float(((unsigned)h) << 16);
}

// ============================ MFMA GEMM ====================================
// C(MxN) = act(A @ B + bias). A: M x K (split bf16 or fp32 if SPLITA).
// B: pre-transposed+split, Bhi/Blo are N x K row-major bf16.
// OUTMODE 0: store fp32 C, no bias/relu. OUTMODE 1: bias+relu, store split bf16.
// Block tile 128x128, BK=32, 256 threads (4 waves, 2x2), wave tile 64x64
// as 4x4 MFMA 16x16x32 tiles. 3 MFMAs per tile pair (hihi, hilo, lohi).
template <int OUTMODE, bool SPLITA>
__global__ __launch_bounds__(256, 2) void gemm_mfma(
    const u16* __restrict__ Ahi, const u16* __restrict__ Alo,
    const float* __restrict__ Af,
    const u16* __restrict__ Bhi, const u16* __restrict__ Blo,
    const float* __restrict__ bias,
    float* __restrict__ Cf, u16* __restrict__ Chi, u16* __restrict__ Clo,
    int M, int N, int K) {
  constexpr int BM = 128, BN = 128, BK = 32, LDK = BK + 8;  // 40 u16 = 80 B row
  __shared__ __align__(16) u16 As[2][BM * LDK];
  __shared__ __align__(16) u16 Bs[2][BN * LDK];

  const int tid = threadIdx.x;
  const int lane = tid & 63;
  const int wid = tid >> 6;
  const int wm = (wid >> 1) * 64;
  const int wn = (wid & 1) * 64;
  const int quad = lane >> 4;
  const int l15 = lane & 15;
  const int m0 = blockIdx.x * BM;
  const int n0 = blockIdx.y * BN;

  // staging: 512 chunks of 8 elems per matrix; thread does chunks tid, tid+256
  const int r1 = tid >> 2;        // rows 0..63
  const int r2 = r1 + 64;         // rows 64..127
  const int kc = (tid & 3) * 8;   // 0,8,16,24

  fx4 zf = {0.f, 0.f, 0.f, 0.f};
  fx4 acc[4][4];
#pragma unroll
  for (int a = 0; a < 4; ++a)
#pragma unroll
    for (int b = 0; b < 4; ++b) acc[a][b] = zf;

  const u16x8 zz = {0, 0, 0, 0, 0, 0, 0, 0};

  for (int k0 = 0; k0 < K; k0 += BK) {
    const bool kok = (k0 + kc) < K;  // K%8==0 -> whole chunk in/out
    u16x8 sa_h[2], sa_l[2], sb_h[2], sb_l[2];

    // ---- A global loads ----
#pragma unroll
    for (int it = 0; it < 2; ++it) {
      const int gm = m0 + (it ? r2 : r1);
      const bool ok = (gm < M) && kok;
      if (!SPLITA) {
        const size_t off = (size_t)gm * K + k0 + kc;
        sa_h[it] = ok ? *(const u16x8*)(Ahi + off) : zz;
        sa_l[it] = ok ? *(const u16x8*)(Alo + off) : zz;
      } else {
        fx4 f0 = zf, f1 = zf;
        if (ok) {
          const float* pp = Af + (size_t)gm * K + k0 + kc;
          f0 = *(const fx4*)pp;
          f1 = *(const fx4*)(pp + 4);
        }
        u16x8 h, l;
#pragma unroll
        for (int j = 0; j < 4; ++j) {
          u16 hb = bf16_rn(f0[j]);
          h[j] = hb;
          l[j] = bf16_rn(f0[j] - bf16_f(hb));
        }
#pragma unroll
        for (int j = 0; j < 4; ++j) {
          u16 hb = bf16_rn(f1[j]);
          h[4 + j] = hb;
          l[4 + j] = bf16_rn(f1[j] - bf16_f(hb));
        }
        sa_h[it] = h;
        sa_l[it] = l;
      }
    }
    // ---- B global loads (pre-transposed N x K) ----
#pragma unroll
    for (int it = 0; it < 2; ++it) {
      const int gn = n0 + (it ? r2 : r1);
      const bool ok = (gn < N) && kok;
      const size_t off = (size_t)gn * K + k0 + kc;
      sb_h[it] = ok ? *(const u16x8*)(Bhi + off) : zz;
      sb_l[it] = ok ? *(const u16x8*)(Blo + off) : zz;
    }

    __syncthreads();  // previous iteration's frag reads complete
    {
      const int wo1 = r1 * LDK + kc;
      const int wo2 = r2 * LDK + kc;
      *(u16x8*)&As[0][wo1] = sa_h[0];
      *(u16x8*)&As[0][wo2] = sa_h[1];
      *(u16x8*)&As[1][wo1] = sa_l[0];
      *(u16x8*)&As[1][wo2] = sa_l[1];
      *(u16x8*)&Bs[0][wo1] = sb_h[0];
      *(u16x8*)&Bs[0][wo2] = sb_h[1];
      *(u16x8*)&Bs[1][wo1] = sb_l[0];
      *(u16x8*)&Bs[1][wo2] = sb_l[1];
    }
    __syncthreads();

    // ---- fragments: lane holds A[m=l15][k=quad*8+j], B[k=quad*8+j][n=l15] ----
    short8 ah[4], al[4], bh[4], bl[4];
#pragma unroll
    for (int t = 0; t < 4; ++t) {
      const int ra = (wm + t * 16 + l15) * LDK + quad * 8;
      ah[t] = *(const short8*)&As[0][ra];
      al[t] = *(const short8*)&As[1][ra];
      const int rb = (wn + t * 16 + l15) * LDK + quad * 8;
      bh[t] = *(const short8*)&Bs[0][rb];
      bl[t] = *(const short8*)&Bs[1][rb];
    }
#pragma unroll
    for (int mt = 0; mt < 4; ++mt)
#pragma unroll
      for (int nt = 0; nt < 4; ++nt) {
        acc[mt][nt] = __builtin_amdgcn_mfma_f32_16x16x32_bf16(ah[mt], bh[nt], acc[mt][nt], 0, 0, 0);
        acc[mt][nt] = __builtin_amdgcn_mfma_f32_16x16x32_bf16(ah[mt], bl[nt], acc[mt][nt], 0, 0, 0);
        acc[mt][nt] = __builtin_amdgcn_mfma_f32_16x16x32_bf16(al[mt], bh[nt], acc[mt][nt], 0, 0, 0);
      }
  }

  // ---- epilogue: D[m = quad*4+r][n = l15] per 16x16 tile ----
#pragma unroll
  for (int mt = 0; mt < 4; ++mt)
#pragma unroll
    for (int nt = 0; nt < 4; ++nt) {
      const int gn = n0 + wn + nt * 16 + l15;
      if (gn >= N) continue;
      const float bv = (OUTMODE == 1) ? bias[gn] : 0.f;
#pragma unroll
      for (int r = 0; r < 4; ++r) {
        const int gm = m0 + wm + mt * 16 + quad * 4 + r;
        if (gm < M) {
          float v = acc[mt][nt][r];
          if (OUTMODE == 1) {
            v = fmaxf(v + bv, 0.f);
            const u16 hb = bf16_rn(v);
            Chi[(size_t)gm * N + gn] = hb;
            Clo[(size_t)gm * N + gn] = bf16_rn(v - bf16_f(hb));
          } else {
            Cf[(size_t)gm * N + gn] = v;
          }
        }
      }
    }
}

// ================= weight prep: transpose + split ==========================
// W: K x N fp32 -> Thi/Tlo: N x K bf16
__global__ __launch_bounds__(256) void transpose_split(
    const float* __restrict__ W, int K, int N,
    u16* __restrict__ Thi, u16* __restrict__ Tlo) {
  __shared__ float tile[32][33];
  const int k0 = blockIdx.x * 32, n0 = blockIdx.y * 32;
  const int tx = threadIdx.x & 31, ty = threadIdx.x >> 5;  // ty 0..7
#pragma unroll
  for (int i = 0; i < 32; i += 8) {
    const int k = k0 + ty + i, n = n0 + tx;
    tile[ty + i][tx] = (k < K && n < N) ? W[(size_t)k * N + n] : 0.f;
  }
  __syncthreads();
#pragma unroll
  for (int i = 0; i < 32; i += 8) {
    const int n = n0 + ty + i, k = k0 + tx;
    if (n < N && k < K) {
      const float f = tile[tx][ty + i];
      const u16 hb = bf16_rn(f);
      Thi[(size_t)n * K + k] = hb;
      Tlo[(size_t)n * K + k] = bf16_rn(f - bf16_f(hb));
    }
  }
}

// ========================= Graph preprocessing =============================
__global__ void count_deg(const int* __restrict__ dst, int E, int* __restrict__ cnt) {
  int e = blockIdx.x * blockDim.x + threadIdx.x;
  if (e < E) atomicAdd(&cnt[dst[e]], 1);
}

__global__ void compute_dinv(const int* __restrict__ cnt, float* __restrict__ dinv, int N) {
  int i = blockIdx.x * blockDim.x + threadIdx.x;
  if (i < N) dinv[i] = rsqrtf((float)(cnt[i] + 1));  // +1 self-loop
}

__global__ void scan_block(const int* __restrict__ cnt, int* __restrict__ partial,
                           int* __restrict__ blocksum, int N) {
  __shared__ int s[256];
  const int t = threadIdx.x;
  const int i = blockIdx.x * 256 + t;
  int v = (i < N) ? cnt[i] : 0;
  s[t] = v;
  __syncthreads();
  for (int off = 1; off < 256; off <<= 1) {
    int u = (t >= off) ? s[t - off] : 0;
    __syncthreads();
    s[t] += u;
    __syncthreads();
  }
  if (i < N) partial[i] = s[t];
  if (t == 255) blocksum[blockIdx.x] = s[255];
}

__global__ void scan_sums(int* __restrict__ blocksum, int NB) {
  __shared__ int s[256];
  const int t = threadIdx.x;
  int v = (t < NB) ? blocksum[t] : 0;
  s[t] = v;
  __syncthreads();
  for (int off = 1; off < 256; off <<= 1) {
    int u = (t >= off) ? s[t - off] : 0;
    __syncthreads();
    s[t] += u;
    __syncthreads();
  }
  if (t < NB) blocksum[t] = s[t] - v;  // exclusive
}

__global__ void finalize_rowptr(const int* __restrict__ partial, const int* __restrict__ blockoff,
                                int* __restrict__ rowptr, int N) {
  int i = blockIdx.x * 256 + threadIdx.x;
  if (i < N) rowptr[i + 1] = partial[i] + blockoff[blockIdx.x];
  if (i == 0) rowptr[0] = 0;
}

__global__ void fill_csr(const int* __restrict__ src, const int* __restrict__ dst, int E,
                         const int* __restrict__ rowptr, int* __restrict__ cursor,
                         int* __restrict__ colidx) {
  int e = blockIdx.x * blockDim.x + threadIdx.x;
  if (e < E) {
    int d = dst[e];
    int p = atomicAdd(&cursor[d], 1);
    colidx[rowptr[d] + p] = src[e];
  }
}

// ================= Message passing + bias + BN + ReLU ======================
// one block per dst node; writes split bf16 (next GEMM's A operand)
__global__ __launch_bounds__(256) void mp_bn_relu(
    const float* __restrict__ H, const int* __restrict__ rowptr,
    const int* __restrict__ colidx, const float* __restrict__ dinv,
    const float* __restrict__ gb, const float* __restrict__ gamma,
    const float* __restrict__ beta, const float* __restrict__ mean,
    const float* __restrict__ var,
    u16* __restrict__ Xh, u16* __restrict__ Xl, int N, int F) {
  const int i = blockIdx.x;
  const int t = threadIdx.x;
  const float di = dinv[i];
  const int c0 = t, c1 = t + 256, c2 = t + 512;
  const float* Hi = H + (size_t)i * F;
  const float wself = di * di;
  float a0 = 0.f, a1 = 0.f, a2 = 0.f;
  if (c0 < F) a0 = wself * Hi[c0];
  if (c1 < F) a1 = wself * Hi[c1];
  if (c2 < F) a2 = wself * Hi[c2];
  const int e0 = rowptr[i], e1 = rowptr[i + 1];
  for (int e = e0; e < e1; ++e) {
    const int s = colidx[e];
    const float w = di * dinv[s];
    const float* Hs = H + (size_t)s * F;
    if (c0 < F) a0 += w * Hs[c0];
    if (c1 < F) a1 += w * Hs[c1];
    if (c2 < F) a2 += w * Hs[c2];
  }
  u16* Oh = Xh + (size_t)i * F;
  u16* Ol = Xl + (size_t)i * F;
  if (c0 < F) {
    float v = (a0 + gb[c0] - mean[c0]) * rsqrtf(var[c0] + EPS_BN) * gamma[c0] + beta[c0];
    v = fmaxf(v, 0.f);
    u16 hb = bf16_rn(v);
    Oh[c0] = hb;
    Ol[c0] = bf16_rn(v - bf16_f(hb));
  }
  if (c1 < F) {
    float v = (a1 + gb[c1] - mean[c1]) * rsqrtf(var[c1] + EPS_BN) * gamma[c1] + beta[c1];
    v = fmaxf(v, 0.f);
    u16 hb = bf16_rn(v);
    Oh[c1] = hb;
    Ol[c1] = bf16_rn(v - bf16_f(hb));
  }
  if (c2 < F) {
    float v = (a2 + gb[c2] - mean[c2]) * rsqrtf(var[c2] + EPS_BN) * gamma[c2] + beta[c2];
    v = fmaxf(v, 0.f);
    u16 hb = bf16_rn(v);
    Oh[c2] = hb;
    Ol[c2] = bf16_rn(v - bf16_f(hb));
  }
}

// ========================= global max pool =================================
__global__ __launch_bounds__(256) void pool_max(
    const u16* __restrict__ Xh, const u16* __restrict__ Xl,
    const int* __restrict__ batch, float* __restrict__ out, int N, int F) {
  const int i = blockIdx.x;
  const int g = batch[i];
  const u16* Hh = Xh + (size_t)i * F;
  const u16* Hl = Xl + (size_t)i * F;
  unsigned int* og = reinterpret_cast<unsigned int*>(out + (size_t)g * F);
  for (int c = threadIdx.x; c < F; c += blockDim.x) {
    const float f = bf16_f(Hh[c]) + bf16_f(Hl[c]);
    atomicMax(&og[c], __float_as_uint(f));
  }
}

// =========================== launch ========================================
extern "C" void kernel_launch(void* const* d_in, const int* in_sizes, int n_in,
                              void* d_out, int out_size, void* d_ws, size_t ws_size,
                              hipStream_t stream) {
  const float* x = (const float*)d_in[0];
  const int* edges = (const int*)d_in[1];
  const int* batch = (const int*)d_in[2];
  const int E = in_sizes[1] / 2;
  const int Nn = in_sizes[2];

  static const int FDS[4] = {80, 160, 400, 600};
  static const int DINS[4] = {3072, 80, 160, 400};
  const float *wa[4], *ba[4], *wb[4], *bb[4], *gw[4], *gb[4], *gamma[4], *beta[4], *mean[4], *var[4];
  for (int i = 0; i < 4; ++i) {
    const int b = 3 + 10 * i;
    wa[i] = (const float*)d_in[b + 0];
    ba[i] = (const float*)d_in[b + 1];
    wb[i] = (const float*)d_in[b + 2];
    bb[i] = (const float*)d_in[b + 3];
    gw[i] = (const float*)d_in[b + 4];
    gb[i] = (const float*)d_in[b + 5];
    gamma[i] = (const float*)d_in[b + 6];
    beta[i] = (const float*)d_in[b + 7];
    mean[i] = (const float*)d_in[b + 8];
    var[i] = (const float*)d_in[b + 9];
  }

  // ---- workspace carve ----
  char* p = (char*)d_ws;
  auto alloc = [&](size_t bytes) {
    char* r = p;
    p += (bytes + 255) & ~(size_t)255;
    return r;
  };
  u16* actA_h = (u16*)alloc((size_t)Nn * 2400 * 2);  // H1 hi (96 MB); H3 aliases head
  u16* actA_l = (u16*)alloc((size_t)Nn * 2400 * 2);  // H1 lo
  u16* actB_h = (u16*)alloc((size_t)Nn * 600 * 2);   // X / H2 hi
  u16* actB_l = (u16*)alloc((size_t)Nn * 600 * 2);   // X / H2 lo
  float* H3 = (float*)actA_h;  // H1 dead when G3 writes H3; MP consumes before next G1

  u16 *waT_h[4], *waT_l[4], *wbT_h[4], *wbT_l[4], *gwT_h[4], *gwT_l[4];
  for (int i = 0; i < 4; ++i) {
    const size_t s1 = (size_t)DINS[i] * 4 * FDS[i];
    const size_t s2 = (size_t)4 * FDS[i] * FDS[i];
    const size_t s3 = (size_t)FDS[i] * FDS[i];
    waT_h[i] = (u16*)alloc(s1 * 2);
    waT_l[i] = (u16*)alloc(s1 * 2);
    wbT_h[i] = (u16*)alloc(s2 * 2);
    wbT_l[i] = (u16*)alloc(s2 * 2);
    gwT_h[i] = (u16*)alloc(s3 * 2);
    gwT_l[i] = (u16*)alloc(s3 * 2);
  }

  int* cnt = (int*)alloc((size_t)Nn * sizeof(int));
  int* cursor = (int*)alloc((size_t)Nn * sizeof(int));
  int* partial = (int*)alloc((size_t)Nn * sizeof(int));
  int* blocksum = (int*)alloc(256 * sizeof(int));
  int* rowptr = (int*)alloc((size_t)(Nn + 1) * sizeof(int));
  int* colidx = (int*)alloc((size_t)E * sizeof(int));
  float* dinv = (float*)alloc((size_t)Nn * sizeof(float));

  const int* srcIdx = edges;
  const int* dstIdx = edges + E;

  // ---- weight prep ----
  auto tsplit = [&](const float* W, int K, int Ncols, u16* Th, u16* Tl) {
    dim3 g((K + 31) / 32, (Ncols + 31) / 32);
    transpose_split<<<g, 256, 0, stream>>>(W, K, Ncols, Th, Tl);
  };
  for (int i = 0; i < 4; ++i) {
    tsplit(wa[i], DINS[i], 4 * FDS[i], waT_h[i], waT_l[i]);
    tsplit(wb[i], 4 * FDS[i], FDS[i], wbT_h[i], wbT_l[i]);
    tsplit(gw[i], FDS[i], FDS[i], gwT_h[i], gwT_l[i]);
  }

  // ---- CSR build ----
  hipMemsetAsync(cnt, 0, (size_t)Nn * sizeof(int), stream);
  hipMemsetAsync(cursor, 0, (size_t)Nn * sizeof(int), stream);
  hipMemsetAsync(d_out, 0, (size_t)out_size * sizeof(float), stream);

  const int EB = (E + 255) / 256;
  const int NB = (Nn + 255) / 256;
  count_deg<<<EB, 256, 0, stream>>>(dstIdx, E, cnt);
  compute_dinv<<<NB, 256, 0, stream>>>(cnt, dinv, Nn);
  scan_block<<<NB, 256, 0, stream>>>(cnt, partial, blocksum, Nn);
  scan_sums<<<1, 256, 0, stream>>>(blocksum, NB);
  finalize_rowptr<<<NB, 256, 0, stream>>>(partial, blocksum, rowptr, Nn);
  fill_csr<<<EB, 256, 0, stream>>>(srcIdx, dstIdx, E, rowptr, cursor, colidx);

  // ---- layers ----
  auto grid_of = [&](int M, int Ncols) { return dim3((M + 127) / 128, (Ncols + 127) / 128); };

  for (int i = 0; i < 4; ++i) {
    const int fd = FDS[i];
    const int hid = 4 * fd;
    const int din = DINS[i];
    // G1: X @ wa + ba, relu -> H1 (split)
    if (i == 0) {
      gemm_mfma<1, true><<<grid_of(Nn, hid), 256, 0, stream>>>(
          nullptr, nullptr, x, waT_h[0], waT_l[0], ba[0],
          nullptr, actA_h, actA_l, Nn, hid, din);
    } else {
      gemm_mfma<1, false><<<grid_of(Nn, hid), 256, 0, stream>>>(
          actB_h, actB_l, nullptr, waT_h[i], waT_l[i], ba[i],
          nullptr, actA_h, actA_l, Nn, hid, din);
    }
    // G2: H1 @ wb + bb, relu -> H2 (split, overwrites X which is dead)
    gemm_mfma<1, false><<<grid_of(Nn, fd), 256, 0, stream>>>(
        actA_h, actA_l, nullptr, wbT_h[i], wbT_l[i], bb[i],
        nullptr, actB_h, actB_l, Nn, fd, hid);
    // G3: H2 @ gw -> H3 (fp32, aliases H1 region which is dead)
    gemm_mfma<0, false><<<grid_of(Nn, fd), 256, 0, stream>>>(
        actB_h, actB_l, nullptr, gwT_h[i], gwT_l[i], nullptr,
        H3, nullptr, nullptr, Nn, fd, fd);
    // MP + bias + BN + ReLU -> X_next (split, overwrites H2 which is dead)
    mp_bn_relu<<<Nn, 256, 0, stream>>>(H3, rowptr, colidx, dinv, gb[i], gamma[i],
                                       beta[i], mean[i], var[i], actB_h, actB_l, Nn, fd);
  }

  pool_max<<<Nn, 256, 0, stream>>>(actB_h, actB_l, batch, (float*)d_out, Nn, 600);
}

// Round 4
// 1933.838 us; speedup vs baseline: 2.0331x; 1.1262x over previous
//
#include <hip/hip_runtime.h>
#include <cstdint>
#include <cstddef>
#include <cmath>

// ---------------------------------------------------------------------------
// Round 4: R3 split-bf16 MFMA GEMMs + three memory-system fixes:
//  - GEMM grid swapped to N-tile-fastest (A-slab L2/L3 reuse; B fits L3)
//  - MP: fx4 vector gathers, 4-wide edge unroll, adaptive block size
//  - pool: sorted-batch segment max (no atomics), batched weight-prep launch
// ---------------------------------------------------------------------------

#define EPS_BN 1e-5f

typedef unsigned short u16;
typedef short short8 __attribute__((ext_vector_type(8)));
typedef u16 u16x8 __attribute__((ext_vector_type(8)));
typedef u16 u16x4 __attribute__((ext_vector_type(4)));
typedef float fx4 __attribute__((ext_vector_type(4)));

__device__ __forceinline__ u16 bf16_rn(float f) {
  unsigned u = __float_as_uint(f);
  return (u16)((u + 0x7FFFu + ((u >> 16) & 1u)) >> 16);
}
__device__ __forceinline__ float bf16_f(u16 h) {
  return __uint_as_float(((unsigned)h) << 16);
}

// ============================ MFMA GEMM ====================================
// C(MxN) = act(A @ B + bias). A: M x K (split bf16, or fp32 if SPLITA).
// B pre-transposed+split: Bhi/Blo are N x K bf16. OUTMODE 0: fp32 C.
// OUTMODE 1: bias+relu -> split bf16. Block 128x128, BK=32, 4 waves (2x2),
// wave 64x64 as 4x4 MFMA 16x16x32 tiles; 3 MFMAs (hihi, hilo, lohi).
// Grid: blockIdx.x = N-tile (fastest) so consecutive blocks reuse the A-slab.
template <int OUTMODE, bool SPLITA>
__global__ __launch_bounds__(256, 2) void gemm_mfma(
    const u16* __restrict__ Ahi, const u16* __restrict__ Alo,
    const float* __restrict__ Af,
    const u16* __restrict__ Bhi, const u16* __restrict__ Blo,
    const float* __restrict__ bias,
    float* __restrict__ Cf, u16* __restrict__ Chi, u16* __restrict__ Clo,
    int M, int N, int K) {
  constexpr int BM = 128, BN = 128, BK = 32, LDK = BK + 8;  // 40 u16 = 80 B row
  __shared__ __align__(16) u16 As[2][BM * LDK];
  __shared__ __align__(16) u16 Bs[2][BN * LDK];

  const int tid = threadIdx.x;
  const int lane = tid & 63;
  const int wid = tid >> 6;
  const int wm = (wid >> 1) * 64;
  const int wn = (wid & 1) * 64;
  const int quad = lane >> 4;
  const int l15 = lane & 15;
  const int m0 = blockIdx.y * BM;   // swapped: y = M-tile
  const int n0 = blockIdx.x * BN;   // x = N-tile (fastest)

  const int r1 = tid >> 2;        // rows 0..63
  const int r2 = r1 + 64;         // rows 64..127
  const int kc = (tid & 3) * 8;   // 0,8,16,24

  fx4 zf = {0.f, 0.f, 0.f, 0.f};
  fx4 acc[4][4];
#pragma unroll
  for (int a = 0; a < 4; ++a)
#pragma unroll
    for (int b = 0; b < 4; ++b) acc[a][b] = zf;

  const u16x8 zz = {0, 0, 0, 0, 0, 0, 0, 0};

  for (int k0 = 0; k0 < K; k0 += BK) {
    const bool kok = (k0 + kc) < K;  // K%8==0 -> whole 8-chunk in/out
    u16x8 sa_h[2], sa_l[2], sb_h[2], sb_l[2];

#pragma unroll
    for (int it = 0; it < 2; ++it) {
      const int gm = m0 + (it ? r2 : r1);
      const bool ok = (gm < M) && kok;
      if (!SPLITA) {
        const size_t off = (size_t)gm * K + k0 + kc;
        sa_h[it] = ok ? *(const u16x8*)(Ahi + off) : zz;
        sa_l[it] = ok ? *(const u16x8*)(Alo + off) : zz;
      } else {
        fx4 f0 = zf, f1 = zf;
        if (ok) {
          const float* pp = Af + (size_t)gm * K + k0 + kc;
          f0 = *(const fx4*)pp;
          f1 = *(const fx4*)(pp + 4);
        }
        u16x8 h, l;
#pragma unroll
        for (int j = 0; j < 4; ++j) {
          u16 hb = bf16_rn(f0[j]);
          h[j] = hb;
          l[j] = bf16_rn(f0[j] - bf16_f(hb));
        }
#pragma unroll
        for (int j = 0; j < 4; ++j) {
          u16 hb = bf16_rn(f1[j]);
          h[4 + j] = hb;
          l[4 + j] = bf16_rn(f1[j] - bf16_f(hb));
        }
        sa_h[it] = h;
        sa_l[it] = l;
      }
    }
#pragma unroll
    for (int it = 0; it < 2; ++it) {
      const int gn = n0 + (it ? r2 : r1);
      const bool ok = (gn < N) && kok;
      const size_t off = (size_t)gn * K + k0 + kc;
      sb_h[it] = ok ? *(const u16x8*)(Bhi + off) : zz;
      sb_l[it] = ok ? *(const u16x8*)(Blo + off) : zz;
    }

    __syncthreads();
    {
      const int wo1 = r1 * LDK + kc;
      const int wo2 = r2 * LDK + kc;
      *(u16x8*)&As[0][wo1] = sa_h[0];
      *(u16x8*)&As[0][wo2] = sa_h[1];
      *(u16x8*)&As[1][wo1] = sa_l[0];
      *(u16x8*)&As[1][wo2] = sa_l[1];
      *(u16x8*)&Bs[0][wo1] = sb_h[0];
      *(u16x8*)&Bs[0][wo2] = sb_h[1];
      *(u16x8*)&Bs[1][wo1] = sb_l[0];
      *(u16x8*)&Bs[1][wo2] = sb_l[1];
    }
    __syncthreads();

    short8 ah[4], al[4], bh[4], bl[4];
#pragma unroll
    for (int t = 0; t < 4; ++t) {
      const int ra = (wm + t * 16 + l15) * LDK + quad * 8;
      ah[t] = *(const short8*)&As[0][ra];
      al[t] = *(const short8*)&As[1][ra];
      const int rb = (wn + t * 16 + l15) * LDK + quad * 8;
      bh[t] = *(const short8*)&Bs[0][rb];
      bl[t] = *(const short8*)&Bs[1][rb];
    }
#pragma unroll
    for (int mt = 0; mt < 4; ++mt)
#pragma unroll
      for (int nt = 0; nt < 4; ++nt) {
        acc[mt][nt] = __builtin_amdgcn_mfma_f32_16x16x32_bf16(ah[mt], bh[nt], acc[mt][nt], 0, 0, 0);
        acc[mt][nt] = __builtin_amdgcn_mfma_f32_16x16x32_bf16(ah[mt], bl[nt], acc[mt][nt], 0, 0, 0);
        acc[mt][nt] = __builtin_amdgcn_mfma_f32_16x16x32_bf16(al[mt], bh[nt], acc[mt][nt], 0, 0, 0);
      }
  }

#pragma unroll
  for (int mt = 0; mt < 4; ++mt)
#pragma unroll
    for (int nt = 0; nt < 4; ++nt) {
      const int gn = n0 + wn + nt * 16 + l15;
      if (gn >= N) continue;
      const float bv = (OUTMODE == 1) ? bias[gn] : 0.f;
#pragma unroll
      for (int r = 0; r < 4; ++r) {
        const int gm = m0 + wm + mt * 16 + quad * 4 + r;
        if (gm < M) {
          float v = acc[mt][nt][r];
          if (OUTMODE == 1) {
            v = fmaxf(v + bv, 0.f);
            const u16 hb = bf16_rn(v);
            Chi[(size_t)gm * N + gn] = hb;
            Clo[(size_t)gm * N + gn] = bf16_rn(v - bf16_f(hb));
          } else {
            Cf[(size_t)gm * N + gn] = v;
          }
        }
      }
    }
}

// ================= weight prep: transpose + split (batched) ================
struct TSJob { const float* W; u16* Th; u16* Tl; int K; int N; int tiles_k; int base; };
struct TSJobs { TSJob j[12]; };

__global__ __launch_bounds__(256) void transpose_split_all(TSJobs jobs, int njobs) {
  const int b = blockIdx.x;
  int ji = 0;
  while (ji + 1 < njobs && jobs.j[ji + 1].base <= b) ++ji;
  const TSJob J = jobs.j[ji];
  const int t = b - J.base;
  const int k0 = (t % J.tiles_k) * 32;
  const int n0 = (t / J.tiles_k) * 32;
  __shared__ float tile[32][33];
  const int tx = threadIdx.x & 31, ty = threadIdx.x >> 5;
#pragma unroll
  for (int i = 0; i < 32; i += 8) {
    const int k = k0 + ty + i, n = n0 + tx;
    tile[ty + i][tx] = (k < J.K && n < J.N) ? J.W[(size_t)k * J.N + n] : 0.f;
  }
  __syncthreads();
#pragma unroll
  for (int i = 0; i < 32; i += 8) {
    const int n = n0 + ty + i, k = k0 + tx;
    if (n < J.N && k < J.K) {
      const float f = tile[tx][ty + i];
      const u16 hb = bf16_rn(f);
      J.Th[(size_t)n * J.K + k] = hb;
      J.Tl[(size_t)n * J.K + k] = bf16_rn(f - bf16_f(hb));
    }
  }
}

// ========================= Graph preprocessing =============================
__global__ void count_deg(const int* __restrict__ dst, int E, int* __restrict__ cnt) {
  int e = blockIdx.x * blockDim.x + threadIdx.x;
  if (e < E) atomicAdd(&cnt[dst[e]], 1);
}

__global__ void compute_dinv(const int* __restrict__ cnt, float* __restrict__ dinv, int N) {
  int i = blockIdx.x * blockDim.x + threadIdx.x;
  if (i < N) dinv[i] = rsqrtf((float)(cnt[i] + 1));  // +1 self-loop
}

__global__ void scan_block(const int* __restrict__ cnt, int* __restrict__ partial,
                           int* __restrict__ blocksum, int N) {
  __shared__ int s[256];
  const int t = threadIdx.x;
  const int i = blockIdx.x * 256 + t;
  int v = (i < N) ? cnt[i] : 0;
  s[t] = v;
  __syncthreads();
  for (int off = 1; off < 256; off <<= 1) {
    int u = (t >= off) ? s[t - off] : 0;
    __syncthreads();
    s[t] += u;
    __syncthreads();
  }
  if (i < N) partial[i] = s[t];
  if (t == 255) blocksum[blockIdx.x] = s[255];
}

__global__ void scan_sums(int* __restrict__ blocksum, int NB) {
  __shared__ int s[256];
  const int t = threadIdx.x;
  int v = (t < NB) ? blocksum[t] : 0;
  s[t] = v;
  __syncthreads();
  for (int off = 1; off < 256; off <<= 1) {
    int u = (t >= off) ? s[t - off] : 0;
    __syncthreads();
    s[t] += u;
    __syncthreads();
  }
  if (t < NB) blocksum[t] = s[t] - v;  // exclusive
}

__global__ void finalize_rowptr(const int* __restrict__ partial, const int* __restrict__ blockoff,
                                int* __restrict__ rowptr, int N) {
  int i = blockIdx.x * 256 + threadIdx.x;
  if (i < N) rowptr[i + 1] = partial[i] + blockoff[blockIdx.x];
  if (i == 0) rowptr[0] = 0;
}

__global__ void fill_csr(const int* __restrict__ src, const int* __restrict__ dst, int E,
                         const int* __restrict__ rowptr, int* __restrict__ cursor,
                         int* __restrict__ colidx) {
  int e = blockIdx.x * blockDim.x + threadIdx.x;
  if (e < E) {
    int d = dst[e];
    int p = atomicAdd(&cursor[d], 1);
    colidx[rowptr[d] + p] = src[e];
  }
}

// ================= Message passing + bias + BN + ReLU ======================
// one block per dst node; thread t owns fx4 chunk t; 4-wide edge unroll.
__global__ void mp_bn_relu(
    const float* __restrict__ H, const int* __restrict__ rowptr,
    const int* __restrict__ colidx, const float* __restrict__ dinv,
    const float* __restrict__ gb, const float* __restrict__ gamma,
    const float* __restrict__ beta, const float* __restrict__ mean,
    const float* __restrict__ var,
    u16* __restrict__ Xh, u16* __restrict__ Xl, int N, int F) {
  const int i = blockIdx.x;
  const int c = threadIdx.x;
  if (c * 4 >= F) return;
  const float di = dinv[i];
  const size_t rowi = (size_t)i * F + c * 4;
  fx4 acc = (di * di) * *(const fx4*)(H + rowi);
  const int e0 = rowptr[i], e1 = rowptr[i + 1];
  int e = e0;
  for (; e + 4 <= e1; e += 4) {
    const int s0 = colidx[e + 0], s1 = colidx[e + 1];
    const int s2 = colidx[e + 2], s3 = colidx[e + 3];
    const float w0 = di * dinv[s0], w1 = di * dinv[s1];
    const float w2 = di * dinv[s2], w3 = di * dinv[s3];
    const fx4 v0 = *(const fx4*)(H + (size_t)s0 * F + c * 4);
    const fx4 v1 = *(const fx4*)(H + (size_t)s1 * F + c * 4);
    const fx4 v2 = *(const fx4*)(H + (size_t)s2 * F + c * 4);
    const fx4 v3 = *(const fx4*)(H + (size_t)s3 * F + c * 4);
    acc += w0 * v0;
    acc += w1 * v1;
    acc += w2 * v2;
    acc += w3 * v3;
  }
  for (; e < e1; ++e) {
    const int s = colidx[e];
    acc += (di * dinv[s]) * *(const fx4*)(H + (size_t)s * F + c * 4);
  }
  u16x4 oh, ol;
#pragma unroll
  for (int j = 0; j < 4; ++j) {
    const int col = c * 4 + j;
    float v = (acc[j] + gb[col] - mean[col]) * rsqrtf(var[col] + EPS_BN) * gamma[col] + beta[col];
    v = fmaxf(v, 0.f);
    const u16 hb = bf16_rn(v);
    oh[j] = hb;
    ol[j] = bf16_rn(v - bf16_f(hb));
  }
  *(u16x4*)(Xh + rowi) = oh;
  *(u16x4*)(Xl + rowi) = ol;
}

// ========================= global max pool (segments) ======================
// batch is sorted -> each group is a contiguous node range (binary search).
__global__ void pool_seg(const u16* __restrict__ Xh, const u16* __restrict__ Xl,
                         const int* __restrict__ batch, float* __restrict__ out,
                         int N, int F) {
  const int g = blockIdx.x;
  int lo = 0, hi = N;
  while (lo < hi) { int m = (lo + hi) >> 1; if (batch[m] < g) lo = m + 1; else hi = m; }
  const int s0 = lo;
  hi = N;
  while (lo < hi) { int m = (lo + hi) >> 1; if (batch[m] <= g) lo = m + 1; else hi = m; }
  const int s1 = lo;
  const int c = threadIdx.x;
  if (c * 4 >= F) return;
  fx4 mx = {-INFINITY, -INFINITY, -INFINITY, -INFINITY};
  for (int i = s0; i < s1; ++i) {
    const size_t off = (size_t)i * F + c * 4;
    const u16x4 h = *(const u16x4*)(Xh + off);
    const u16x4 l = *(const u16x4*)(Xl + off);
#pragma unroll
    for (int j = 0; j < 4; ++j) mx[j] = fmaxf(mx[j], bf16_f(h[j]) + bf16_f(l[j]));
  }
  *(fx4*)(out + (size_t)g * F + c * 4) = mx;
}

// =========================== launch ========================================
extern "C" void kernel_launch(void* const* d_in, const int* in_sizes, int n_in,
                              void* d_out, int out_size, void* d_ws, size_t ws_size,
                              hipStream_t stream) {
  const float* x = (const float*)d_in[0];
  const int* edges = (const int*)d_in[1];
  const int* batch = (const int*)d_in[2];
  const int E = in_sizes[1] / 2;
  const int Nn = in_sizes[2];

  static const int FDS[4] = {80, 160, 400, 600};
  static const int DINS[4] = {3072, 80, 160, 400};
  const float *wa[4], *ba[4], *wb[4], *bb[4], *gw[4], *gb[4], *gamma[4], *beta[4], *mean[4], *var[4];
  for (int i = 0; i < 4; ++i) {
    const int b = 3 + 10 * i;
    wa[i] = (const float*)d_in[b + 0];
    ba[i] = (const float*)d_in[b + 1];
    wb[i] = (const float*)d_in[b + 2];
    bb[i] = (const float*)d_in[b + 3];
    gw[i] = (const float*)d_in[b + 4];
    gb[i] = (const float*)d_in[b + 5];
    gamma[i] = (const float*)d_in[b + 6];
    beta[i] = (const float*)d_in[b + 7];
    mean[i] = (const float*)d_in[b + 8];
    var[i] = (const float*)d_in[b + 9];
  }

  // ---- workspace carve ----
  char* p = (char*)d_ws;
  auto alloc = [&](size_t bytes) {
    char* r = p;
    p += (bytes + 255) & ~(size_t)255;
    return r;
  };
  u16* actA_h = (u16*)alloc((size_t)Nn * 2400 * 2);  // H1 hi; H3(fp32) aliases head
  u16* actA_l = (u16*)alloc((size_t)Nn * 2400 * 2);  // H1 lo
  u16* actB_h = (u16*)alloc((size_t)Nn * 600 * 2);   // X / H2 hi
  u16* actB_l = (u16*)alloc((size_t)Nn * 600 * 2);   // X / H2 lo
  float* H3 = (float*)actA_h;  // H1 dead when G3 writes H3; MP consumes before next G1

  u16 *waT_h[4], *waT_l[4], *wbT_h[4], *wbT_l[4], *gwT_h[4], *gwT_l[4];
  for (int i = 0; i < 4; ++i) {
    const size_t s1 = (size_t)DINS[i] * 4 * FDS[i];
    const size_t s2 = (size_t)4 * FDS[i] * FDS[i];
    const size_t s3 = (size_t)FDS[i] * FDS[i];
    waT_h[i] = (u16*)alloc(s1 * 2);
    waT_l[i] = (u16*)alloc(s1 * 2);
    wbT_h[i] = (u16*)alloc(s2 * 2);
    wbT_l[i] = (u16*)alloc(s2 * 2);
    gwT_h[i] = (u16*)alloc(s3 * 2);
    gwT_l[i] = (u16*)alloc(s3 * 2);
  }

  int* cnt = (int*)alloc((size_t)Nn * sizeof(int));
  int* cursor = (int*)alloc((size_t)Nn * sizeof(int));
  int* partial = (int*)alloc((size_t)Nn * sizeof(int));
  int* blocksum = (int*)alloc(256 * sizeof(int));
  int* rowptr = (int*)alloc((size_t)(Nn + 1) * sizeof(int));
  int* colidx = (int*)alloc((size_t)E * sizeof(int));
  float* dinv = (float*)alloc((size_t)Nn * sizeof(float));

  const int* srcIdx = edges;
  const int* dstIdx = edges + E;

  // ---- weight prep: one batched launch for all 12 transpose+splits ----
  {
    TSJobs jobs;
    int base = 0, ji = 0;
    auto addjob = [&](const float* W, int K, int Ncols, u16* Th, u16* Tl) {
      const int tk = (K + 31) / 32, tn = (Ncols + 31) / 32;
      jobs.j[ji++] = TSJob{W, Th, Tl, K, Ncols, tk, base};
      base += tk * tn;
    };
    for (int i = 0; i < 4; ++i) {
      addjob(wa[i], DINS[i], 4 * FDS[i], waT_h[i], waT_l[i]);
      addjob(wb[i], 4 * FDS[i], FDS[i], wbT_h[i], wbT_l[i]);
      addjob(gw[i], FDS[i], FDS[i], gwT_h[i], gwT_l[i]);
    }
    transpose_split_all<<<base, 256, 0, stream>>>(jobs, 12);
  }

  // ---- CSR build ----
  hipMemsetAsync(cnt, 0, (size_t)Nn * sizeof(int), stream);
  hipMemsetAsync(cursor, 0, (size_t)Nn * sizeof(int), stream);

  const int EB = (E + 255) / 256;
  const int NB = (Nn + 255) / 256;
  count_deg<<<EB, 256, 0, stream>>>(dstIdx, E, cnt);
  compute_dinv<<<NB, 256, 0, stream>>>(cnt, dinv, Nn);
  scan_block<<<NB, 256, 0, stream>>>(cnt, partial, blocksum, Nn);
  scan_sums<<<1, 256, 0, stream>>>(blocksum, NB);
  finalize_rowptr<<<NB, 256, 0, stream>>>(partial, blocksum, rowptr, Nn);
  fill_csr<<<EB, 256, 0, stream>>>(srcIdx, dstIdx, E, rowptr, cursor, colidx);

  // ---- layers ----
  auto grid_of = [&](int M, int Ncols) {
    return dim3((Ncols + 127) / 128, (M + 127) / 128);  // N-tile fastest
  };

  for (int i = 0; i < 4; ++i) {
    const int fd = FDS[i];
    const int hid = 4 * fd;
    const int din = DINS[i];
    // G1: X @ wa + ba, relu -> H1 (split)
    if (i == 0) {
      gemm_mfma<1, true><<<grid_of(Nn, hid), 256, 0, stream>>>(
          nullptr, nullptr, x, waT_h[0], waT_l[0], ba[0],
          nullptr, actA_h, actA_l, Nn, hid, din);
    } else {
      gemm_mfma<1, false><<<grid_of(Nn, hid), 256, 0, stream>>>(
          actB_h, actB_l, nullptr, waT_h[i], waT_l[i], ba[i],
          nullptr, actA_h, actA_l, Nn, hid, din);
    }
    // G2: H1 @ wb + bb, relu -> H2 (split)
    gemm_mfma<1, false><<<grid_of(Nn, fd), 256, 0, stream>>>(
        actA_h, actA_l, nullptr, wbT_h[i], wbT_l[i], bb[i],
        nullptr, actB_h, actB_l, Nn, fd, hid);
    // G3: H2 @ gw -> H3 (fp32, aliases H1 region)
    gemm_mfma<0, false><<<grid_of(Nn, fd), 256, 0, stream>>>(
        actB_h, actB_l, nullptr, gwT_h[i], gwT_l[i], nullptr,
        H3, nullptr, nullptr, Nn, fd, fd);
    // MP + bias + BN + ReLU -> X_next (split)
    int bs = (((fd / 4) + 63) / 64) * 64;
    if (bs > 256) bs = 256;
    mp_bn_relu<<<Nn, bs, 0, stream>>>(H3, rowptr, colidx, dinv, gb[i], gamma[i],
                                      beta[i], mean[i], var[i], actB_h, actB_l, Nn, fd);
  }

  pool_seg<<<out_size / 600, 192, 0, stream>>>(actB_h, actB_l, batch, (float*)d_out, Nn, 600);
}

// Round 5
// 1775.030 us; speedup vs baseline: 2.2150x; 1.0895x over previous
//
#include <hip/hip_runtime.h>
#include <cstdint>
#include <cstddef>
#include <cmath>

// ---------------------------------------------------------------------------
// Round 5: R4 + XCD-ownership tile swizzle for all GEMMs.
// Blocks launched on a 1D grid; block b is presumed to run on XCD b%8
// (round-robin dispatch). Each XCD owns M-tiles mt%8==x and sweeps all
// N-tiles of one owned M-tile before advancing -> each A-slab is fetched
// into exactly one XCD L2, once; B stays L3-resident.
// GEMM core: split-bf16 (hi/lo) 3-MFMA, 128x128x32 tiles, 16x16x32 bf16.
// ---------------------------------------------------------------------------

#define EPS_BN 1e-5f

typedef unsigned short u16;
typedef short short8 __attribute__((ext_vector_type(8)));
typedef u16 u16x8 __attribute__((ext_vector_type(8)));
typedef u16 u16x4 __attribute__((ext_vector_type(4)));
typedef float fx4 __attribute__((ext_vector_type(4)));

__device__ __forceinline__ u16 bf16_rn(float f) {
  unsigned u = __float_as_uint(f);
  return (u16)((u + 0x7FFFu + ((u >> 16) & 1u)) >> 16);
}
__device__ __forceinline__ float bf16_f(u16 h) {
  return __uint_as_float(((unsigned)h) << 16);
}

// ---- XCD-ownership swizzle: bijection blockIdx -> (mt, nt) ----------------
// XCD x owns M-tiles {x, x+8, ...}; slot order sweeps N fastest within an
// owned M-tile. T%8 != 0 makes per-XCD block counts != owned-tile counts;
// overflow blocks take the unassigned slots of deficit XCDs, in rank order.
__device__ __forceinline__ void map_tile(int b, int tm, int tn, int T,
                                         int& mt, int& nt) {
  const int x = b & 7;
  const int s = b >> 3;
  const int cap = ((tm - x + 7) >> 3) * tn;  // slots in x's owned region
  if (s < cap) {
    const int q = s / tn;
    mt = x + (q << 3);
    nt = s - q * tn;
    return;
  }
  int r = s - cap;  // overflow rank (within this XCD's overflow)
  for (int xp = 0; xp < x; ++xp) {
    const int nbp = (T - xp + 7) >> 3;              // blocks with b%8==xp
    const int capp = ((tm - xp + 7) >> 3) * tn;
    if (nbp > capp) r += nbp - capp;                // their overflow count
  }
  for (int xq = 0; xq < 8; ++xq) {
    const int nbq = (T - xq + 7) >> 3;
    const int capq = ((tm - xq + 7) >> 3) * tn;
    const int def = capq - nbq;                     // unassigned slots
    if (def > 0) {
      if (r < def) {
        const int sq = nbq + r;
        const int q = sq / tn;
        mt = xq + (q << 3);
        nt = sq - q * tn;
        return;
      }
      r -= def;
    }
  }
  mt = 0; nt = 0;  // unreachable
}

// ============================ MFMA GEMM ====================================
// C(MxN) = act(A @ B + bias). A: M x K (split bf16, or fp32 if SPLITA).
// B pre-transposed+split: Bhi/Blo are N x K bf16. OUTMODE 0: fp32 C.
// OUTMODE 1: bias+relu -> split bf16. Block 128x128, BK=32, 4 waves (2x2),
// wave 64x64 as 4x4 MFMA 16x16x32 tiles; 3 MFMAs (hihi, hilo, lohi).
template <int OUTMODE, bool SPLITA>
__global__ __launch_bounds__(256, 2) void gemm_mfma(
    const u16* __restrict__ Ahi, const u16* __restrict__ Alo,
    const float* __restrict__ Af,
    const u16* __restrict__ Bhi, const u16* __restrict__ Blo,
    const float* __restrict__ bias,
    float* __restrict__ Cf, u16* __restrict__ Chi, u16* __restrict__ Clo,
    int M, int N, int K, int tm, int tn) {
  constexpr int BM = 128, BN = 128, BK = 32, LDK = BK + 8;  // 40 u16 = 80 B row
  __shared__ __align__(16) u16 As[2][BM * LDK];
  __shared__ __align__(16) u16 Bs[2][BN * LDK];

  int mt, nt;
  map_tile(blockIdx.x, tm, tn, tm * tn, mt, nt);
  const int m0 = mt * BM;
  const int n0 = nt * BN;

  const int tid = threadIdx.x;
  const int lane = tid & 63;
  const int wid = tid >> 6;
  const int wm = (wid >> 1) * 64;
  const int wn = (wid & 1) * 64;
  const int quad = lane >> 4;
  const int l15 = lane & 15;

  const int r1 = tid >> 2;        // rows 0..63
  const int r2 = r1 + 64;         // rows 64..127
  const int kc = (tid & 3) * 8;   // 0,8,16,24

  fx4 zf = {0.f, 0.f, 0.f, 0.f};
  fx4 acc[4][4];
#pragma unroll
  for (int a = 0; a < 4; ++a)
#pragma unroll
    for (int b = 0; b < 4; ++b) acc[a][b] = zf;

  const u16x8 zz = {0, 0, 0, 0, 0, 0, 0, 0};

  for (int k0 = 0; k0 < K; k0 += BK) {
    const bool kok = (k0 + kc) < K;  // K%8==0 -> whole 8-chunk in/out
    u16x8 sa_h[2], sa_l[2], sb_h[2], sb_l[2];

#pragma unroll
    for (int it = 0; it < 2; ++it) {
      const int gm = m0 + (it ? r2 : r1);
      const bool ok = (gm < M) && kok;
      if (!SPLITA) {
        const size_t off = (size_t)gm * K + k0 + kc;
        sa_h[it] = ok ? *(const u16x8*)(Ahi + off) : zz;
        sa_l[it] = ok ? *(const u16x8*)(Alo + off) : zz;
      } else {
        fx4 f0 = zf, f1 = zf;
        if (ok) {
          const float* pp = Af + (size_t)gm * K + k0 + kc;
          f0 = *(const fx4*)pp;
          f1 = *(const fx4*)(pp + 4);
        }
        u16x8 h, l;
#pragma unroll
        for (int j = 0; j < 4; ++j) {
          u16 hb = bf16_rn(f0[j]);
          h[j] = hb;
          l[j] = bf16_rn(f0[j] - bf16_f(hb));
        }
#pragma unroll
        for (int j = 0; j < 4; ++j) {
          u16 hb = bf16_rn(f1[j]);
          h[4 + j] = hb;
          l[4 + j] = bf16_rn(f1[j] - bf16_f(hb));
        }
        sa_h[it] = h;
        sa_l[it] = l;
      }
    }
#pragma unroll
    for (int it = 0; it < 2; ++it) {
      const int gn = n0 + (it ? r2 : r1);
      const bool ok = (gn < N) && kok;
      const size_t off = (size_t)gn * K + k0 + kc;
      sb_h[it] = ok ? *(const u16x8*)(Bhi + off) : zz;
      sb_l[it] = ok ? *(const u16x8*)(Blo + off) : zz;
    }

    __syncthreads();
    {
      const int wo1 = r1 * LDK + kc;
      const int wo2 = r2 * LDK + kc;
      *(u16x8*)&As[0][wo1] = sa_h[0];
      *(u16x8*)&As[0][wo2] = sa_h[1];
      *(u16x8*)&As[1][wo1] = sa_l[0];
      *(u16x8*)&As[1][wo2] = sa_l[1];
      *(u16x8*)&Bs[0][wo1] = sb_h[0];
      *(u16x8*)&Bs[0][wo2] = sb_h[1];
      *(u16x8*)&Bs[1][wo1] = sb_l[0];
      *(u16x8*)&Bs[1][wo2] = sb_l[1];
    }
    __syncthreads();

    short8 ah[4], al[4], bh[4], bl[4];
#pragma unroll
    for (int t = 0; t < 4; ++t) {
      const int ra = (wm + t * 16 + l15) * LDK + quad * 8;
      ah[t] = *(const short8*)&As[0][ra];
      al[t] = *(const short8*)&As[1][ra];
      const int rb = (wn + t * 16 + l15) * LDK + quad * 8;
      bh[t] = *(const short8*)&Bs[0][rb];
      bl[t] = *(const short8*)&Bs[1][rb];
    }
#pragma unroll
    for (int mt2 = 0; mt2 < 4; ++mt2)
#pragma unroll
      for (int nt2 = 0; nt2 < 4; ++nt2) {
        acc[mt2][nt2] = __builtin_amdgcn_mfma_f32_16x16x32_bf16(ah[mt2], bh[nt2], acc[mt2][nt2], 0, 0, 0);
        acc[mt2][nt2] = __builtin_amdgcn_mfma_f32_16x16x32_bf16(ah[mt2], bl[nt2], acc[mt2][nt2], 0, 0, 0);
        acc[mt2][nt2] = __builtin_amdgcn_mfma_f32_16x16x32_bf16(al[mt2], bh[nt2], acc[mt2][nt2], 0, 0, 0);
      }
  }

#pragma unroll
  for (int mt2 = 0; mt2 < 4; ++mt2)
#pragma unroll
    for (int nt2 = 0; nt2 < 4; ++nt2) {
      const int gn = n0 + wn + nt2 * 16 + l15;
      if (gn >= N) continue;
      const float bv = (OUTMODE == 1) ? bias[gn] : 0.f;
#pragma unroll
      for (int r = 0; r < 4; ++r) {
        const int gm = m0 + wm + mt2 * 16 + quad * 4 + r;
        if (gm < M) {
          float v = acc[mt2][nt2][r];
          if (OUTMODE == 1) {
            v = fmaxf(v + bv, 0.f);
            const u16 hb = bf16_rn(v);
            Chi[(size_t)gm * N + gn] = hb;
            Clo[(size_t)gm * N + gn] = bf16_rn(v - bf16_f(hb));
          } else {
            Cf[(size_t)gm * N + gn] = v;
          }
        }
      }
    }
}

// ================= weight prep: transpose + split (batched) ================
struct TSJob { const float* W; u16* Th; u16* Tl; int K; int N; int tiles_k; int base; };
struct TSJobs { TSJob j[12]; };

__global__ __launch_bounds__(256) void transpose_split_all(TSJobs jobs, int njobs) {
  const int b = blockIdx.x;
  int ji = 0;
  while (ji + 1 < njobs && jobs.j[ji + 1].base <= b) ++ji;
  const TSJob J = jobs.j[ji];
  const int t = b - J.base;
  const int k0 = (t % J.tiles_k) * 32;
  const int n0 = (t / J.tiles_k) * 32;
  __shared__ float tile[32][33];
  const int tx = threadIdx.x & 31, ty = threadIdx.x >> 5;
#pragma unroll
  for (int i = 0; i < 32; i += 8) {
    const int k = k0 + ty + i, n = n0 + tx;
    tile[ty + i][tx] = (k < J.K && n < J.N) ? J.W[(size_t)k * J.N + n] : 0.f;
  }
  __syncthreads();
#pragma unroll
  for (int i = 0; i < 32; i += 8) {
    const int n = n0 + ty + i, k = k0 + tx;
    if (n < J.N && k < J.K) {
      const float f = tile[tx][ty + i];
      const u16 hb = bf16_rn(f);
      J.Th[(size_t)n * J.K + k] = hb;
      J.Tl[(size_t)n * J.K + k] = bf16_rn(f - bf16_f(hb));
    }
  }
}

// ========================= Graph preprocessing =============================
__global__ void count_deg(const int* __restrict__ dst, int E, int* __restrict__ cnt) {
  int e = blockIdx.x * blockDim.x + threadIdx.x;
  if (e < E) atomicAdd(&cnt[dst[e]], 1);
}

__global__ void compute_dinv(const int* __restrict__ cnt, float* __restrict__ dinv, int N) {
  int i = blockIdx.x * blockDim.x + threadIdx.x;
  if (i < N) dinv[i] = rsqrtf((float)(cnt[i] + 1));  // +1 self-loop
}

__global__ void scan_block(const int* __restrict__ cnt, int* __restrict__ partial,
                           int* __restrict__ blocksum, int N) {
  __shared__ int s[256];
  const int t = threadIdx.x;
  const int i = blockIdx.x * 256 + t;
  int v = (i < N) ? cnt[i] : 0;
  s[t] = v;
  __syncthreads();
  for (int off = 1; off < 256; off <<= 1) {
    int u = (t >= off) ? s[t - off] : 0;
    __syncthreads();
    s[t] += u;
    __syncthreads();
  }
  if (i < N) partial[i] = s[t];
  if (t == 255) blocksum[blockIdx.x] = s[255];
}

__global__ void scan_sums(int* __restrict__ blocksum, int NB) {
  __shared__ int s[256];
  const int t = threadIdx.x;
  int v = (t < NB) ? blocksum[t] : 0;
  s[t] = v;
  __syncthreads();
  for (int off = 1; off < 256; off <<= 1) {
    int u = (t >= off) ? s[t - off] : 0;
    __syncthreads();
    s[t] += u;
    __syncthreads();
  }
  if (t < NB) blocksum[t] = s[t] - v;  // exclusive
}

__global__ void finalize_rowptr(const int* __restrict__ partial, const int* __restrict__ blockoff,
                                int* __restrict__ rowptr, int N) {
  int i = blockIdx.x * 256 + threadIdx.x;
  if (i < N) rowptr[i + 1] = partial[i] + blockoff[blockIdx.x];
  if (i == 0) rowptr[0] = 0;
}

__global__ void fill_csr(const int* __restrict__ src, const int* __restrict__ dst, int E,
                         const int* __restrict__ rowptr, int* __restrict__ cursor,
                         int* __restrict__ colidx) {
  int e = blockIdx.x * blockDim.x + threadIdx.x;
  if (e < E) {
    int d = dst[e];
    int p = atomicAdd(&cursor[d], 1);
    colidx[rowptr[d] + p] = src[e];
  }
}

// ================= Message passing + bias + BN + ReLU ======================
// one block per dst node; thread t owns fx4 chunk t; 4-wide edge unroll.
__global__ void mp_bn_relu(
    const float* __restrict__ H, const int* __restrict__ rowptr,
    const int* __restrict__ colidx, const float* __restrict__ dinv,
    const float* __restrict__ gb, const float* __restrict__ gamma,
    const float* __restrict__ beta, const float* __restrict__ mean,
    const float* __restrict__ var,
    u16* __restrict__ Xh, u16* __restrict__ Xl, int N, int F) {
  const int i = blockIdx.x;
  const int c = threadIdx.x;
  if (c * 4 >= F) return;
  const float di = dinv[i];
  const size_t rowi = (size_t)i * F + c * 4;
  fx4 acc = (di * di) * *(const fx4*)(H + rowi);
  const int e0 = rowptr[i], e1 = rowptr[i + 1];
  int e = e0;
  for (; e + 4 <= e1; e += 4) {
    const int s0 = colidx[e + 0], s1 = colidx[e + 1];
    const int s2 = colidx[e + 2], s3 = colidx[e + 3];
    const float w0 = di * dinv[s0], w1 = di * dinv[s1];
    const float w2 = di * dinv[s2], w3 = di * dinv[s3];
    const fx4 v0 = *(const fx4*)(H + (size_t)s0 * F + c * 4);
    const fx4 v1 = *(const fx4*)(H + (size_t)s1 * F + c * 4);
    const fx4 v2 = *(const fx4*)(H + (size_t)s2 * F + c * 4);
    const fx4 v3 = *(const fx4*)(H + (size_t)s3 * F + c * 4);
    acc += w0 * v0;
    acc += w1 * v1;
    acc += w2 * v2;
    acc += w3 * v3;
  }
  for (; e < e1; ++e) {
    const int s = colidx[e];
    acc += (di * dinv[s]) * *(const fx4*)(H + (size_t)s * F + c * 4);
  }
  u16x4 oh, ol;
#pragma unroll
  for (int j = 0; j < 4; ++j) {
    const int col = c * 4 + j;
    float v = (acc[j] + gb[col] - mean[col]) * rsqrtf(var[col] + EPS_BN) * gamma[col] + beta[col];
    v = fmaxf(v, 0.f);
    const u16 hb = bf16_rn(v);
    oh[j] = hb;
    ol[j] = bf16_rn(v - bf16_f(hb));
  }
  *(u16x4*)(Xh + rowi) = oh;
  *(u16x4*)(Xl + rowi) = ol;
}

// ========================= global max pool (segments) ======================
// batch is sorted -> each group is a contiguous node range (binary search).
__global__ void pool_seg(const u16* __restrict__ Xh, const u16* __restrict__ Xl,
                         const int* __restrict__ batch, float* __restrict__ out,
                         int N, int F) {
  const int g = blockIdx.x;
  int lo = 0, hi = N;
  while (lo < hi) { int m = (lo + hi) >> 1; if (batch[m] < g) lo = m + 1; else hi = m; }
  const int s0 = lo;
  hi = N;
  while (lo < hi) { int m = (lo + hi) >> 1; if (batch[m] <= g) lo = m + 1; else hi = m; }
  const int s1 = lo;
  const int c = threadIdx.x;
  if (c * 4 >= F) return;
  fx4 mx = {-INFINITY, -INFINITY, -INFINITY, -INFINITY};
  for (int i = s0; i < s1; ++i) {
    const size_t off = (size_t)i * F + c * 4;
    const u16x4 h = *(const u16x4*)(Xh + off);
    const u16x4 l = *(const u16x4*)(Xl + off);
#pragma unroll
    for (int j = 0; j < 4; ++j) mx[j] = fmaxf(mx[j], bf16_f(h[j]) + bf16_f(l[j]));
  }
  *(fx4*)(out + (size_t)g * F + c * 4) = mx;
}

// =========================== launch ========================================
extern "C" void kernel_launch(void* const* d_in, const int* in_sizes, int n_in,
                              void* d_out, int out_size, void* d_ws, size_t ws_size,
                              hipStream_t stream) {
  const float* x = (const float*)d_in[0];
  const int* edges = (const int*)d_in[1];
  const int* batch = (const int*)d_in[2];
  const int E = in_sizes[1] / 2;
  const int Nn = in_sizes[2];

  static const int FDS[4] = {80, 160, 400, 600};
  static const int DINS[4] = {3072, 80, 160, 400};
  const float *wa[4], *ba[4], *wb[4], *bb[4], *gw[4], *gb[4], *gamma[4], *beta[4], *mean[4], *var[4];
  for (int i = 0; i < 4; ++i) {
    const int b = 3 + 10 * i;
    wa[i] = (const float*)d_in[b + 0];
    ba[i] = (const float*)d_in[b + 1];
    wb[i] = (const float*)d_in[b + 2];
    bb[i] = (const float*)d_in[b + 3];
    gw[i] = (const float*)d_in[b + 4];
    gb[i] = (const float*)d_in[b + 5];
    gamma[i] = (const float*)d_in[b + 6];
    beta[i] = (const float*)d_in[b + 7];
    mean[i] = (const float*)d_in[b + 8];
    var[i] = (const float*)d_in[b + 9];
  }

  // ---- workspace carve ----
  char* p = (char*)d_ws;
  auto alloc = [&](size_t bytes) {
    char* r = p;
    p += (bytes + 255) & ~(size_t)255;
    return r;
  };
  u16* actA_h = (u16*)alloc((size_t)Nn * 2400 * 2);  // H1 hi; H3(fp32) aliases head
  u16* actA_l = (u16*)alloc((size_t)Nn * 2400 * 2);  // H1 lo
  u16* actB_h = (u16*)alloc((size_t)Nn * 600 * 2);   // X / H2 hi
  u16* actB_l = (u16*)alloc((size_t)Nn * 600 * 2);   // X / H2 lo
  float* H3 = (float*)actA_h;  // H1 dead when G3 writes H3; MP consumes before next G1

  u16 *waT_h[4], *waT_l[4], *wbT_h[4], *wbT_l[4], *gwT_h[4], *gwT_l[4];
  for (int i = 0; i < 4; ++i) {
    const size_t s1 = (size_t)DINS[i] * 4 * FDS[i];
    const size_t s2 = (size_t)4 * FDS[i] * FDS[i];
    const size_t s3 = (size_t)FDS[i] * FDS[i];
    waT_h[i] = (u16*)alloc(s1 * 2);
    waT_l[i] = (u16*)alloc(s1 * 2);
    wbT_h[i] = (u16*)alloc(s2 * 2);
    wbT_l[i] = (u16*)alloc(s2 * 2);
    gwT_h[i] = (u16*)alloc(s3 * 2);
    gwT_l[i] = (u16*)alloc(s3 * 2);
  }

  int* cnt = (int*)alloc((size_t)Nn * sizeof(int));
  int* cursor = (int*)alloc((size_t)Nn * sizeof(int));
  int* partial = (int*)alloc((size_t)Nn * sizeof(int));
  int* blocksum = (int*)alloc(256 * sizeof(int));
  int* rowptr = (int*)alloc((size_t)(Nn + 1) * sizeof(int));
  int* colidx = (int*)alloc((size_t)E * sizeof(int));
  float* dinv = (float*)alloc((size_t)Nn * sizeof(float));

  const int* srcIdx = edges;
  const int* dstIdx = edges + E;

  // ---- weight prep: one batched launch for all 12 transpose+splits ----
  {
    TSJobs jobs;
    int base = 0, ji = 0;
    auto addjob = [&](const float* W, int K, int Ncols, u16* Th, u16* Tl) {
      const int tk = (K + 31) / 32, tn = (Ncols + 31) / 32;
      jobs.j[ji++] = TSJob{W, Th, Tl, K, Ncols, tk, base};
      base += tk * tn;
    };
    for (int i = 0; i < 4; ++i) {
      addjob(wa[i], DINS[i], 4 * FDS[i], waT_h[i], waT_l[i]);
      addjob(wb[i], 4 * FDS[i], FDS[i], wbT_h[i], wbT_l[i]);
      addjob(gw[i], FDS[i], FDS[i], gwT_h[i], gwT_l[i]);
    }
    transpose_split_all<<<base, 256, 0, stream>>>(jobs, 12);
  }

  // ---- CSR build ----
  hipMemsetAsync(cnt, 0, (size_t)Nn * sizeof(int), stream);
  hipMemsetAsync(cursor, 0, (size_t)Nn * sizeof(int), stream);

  const int EB = (E + 255) / 256;
  const int NB = (Nn + 255) / 256;
  count_deg<<<EB, 256, 0, stream>>>(dstIdx, E, cnt);
  compute_dinv<<<NB, 256, 0, stream>>>(cnt, dinv, Nn);
  scan_block<<<NB, 256, 0, stream>>>(cnt, partial, blocksum, Nn);
  scan_sums<<<1, 256, 0, stream>>>(blocksum, NB);
  finalize_rowptr<<<NB, 256, 0, stream>>>(partial, blocksum, rowptr, Nn);
  fill_csr<<<EB, 256, 0, stream>>>(srcIdx, dstIdx, E, rowptr, cursor, colidx);

  // ---- layers ----
  for (int i = 0; i < 4; ++i) {
    const int fd = FDS[i];
    const int hid = 4 * fd;
    const int din = DINS[i];
    const int tm = (Nn + 127) / 128;

    // G1: X @ wa + ba, relu -> H1 (split)
    {
      const int tn = (hid + 127) / 128;
      if (i == 0) {
        gemm_mfma<1, true><<<tm * tn, 256, 0, stream>>>(
            nullptr, nullptr, x, waT_h[0], waT_l[0], ba[0],
            nullptr, actA_h, actA_l, Nn, hid, din, tm, tn);
      } else {
        gemm_mfma<1, false><<<tm * tn, 256, 0, stream>>>(
            actB_h, actB_l, nullptr, waT_h[i], waT_l[i], ba[i],
            nullptr, actA_h, actA_l, Nn, hid, din, tm, tn);
      }
    }
    // G2: H1 @ wb + bb, relu -> H2 (split)
    {
      const int tn = (fd + 127) / 128;
      gemm_mfma<1, false><<<tm * tn, 256, 0, stream>>>(
          actA_h, actA_l, nullptr, wbT_h[i], wbT_l[i], bb[i],
          nullptr, actB_h, actB_l, Nn, fd, hid, tm, tn);
    }
    // G3: H2 @ gw -> H3 (fp32, aliases H1 region)
    {
      const int tn = (fd + 127) / 128;
      gemm_mfma<0, false><<<tm * tn, 256, 0, stream>>>(
          actB_h, actB_l, nullptr, gwT_h[i], gwT_l[i], nullptr,
          H3, nullptr, nullptr, Nn, fd, fd, tm, tn);
    }
    // MP + bias + BN + ReLU -> X_next (split)
    int bs = (((fd / 4) + 63) / 64) * 64;
    if (bs > 256) bs = 256;
    mp_bn_relu<<<Nn, bs, 0, stream>>>(H3, rowptr, colidx, dinv, gb[i], gamma[i],
                                      beta[i], mean[i], var[i], actB_h, actB_l, Nn, fd);
  }

  pool_seg<<<out_size / 600, 192, 0, stream>>>(actB_h, actB_l, batch, (float*)d_out, Nn, 600);
}